// Round 13
// baseline (156.335 us; speedup 1.0000x reference)
//
#include <hip/hip_runtime.h>

#define U_CNT 100000
#define I_CNT 50000
#define DIM   64
#define E_CNT 1250000

#define NB      256   // buckets per CSR
#define SHIFT_U 9     // 512 rows/bucket (U)
#define SHIFT_I 8     // 256 rows/bucket (I)
#define T1      2048  // partition tile (edges per block)  [was 4096: 62KB LDS -> 2 blk/CU]
#define EPT1    8     // edges per thread in partition
#define CAP_B   8192  // fixed capacity per bucket (mean 6400, +22 sigma)
#define WQBITS  15    // record = (src << 15) | top15-of-fp32-weight (sign-less bf16)
#define CONVB   1024  // conv blocks appended to the build launch

typedef float floatx2 __attribute__((ext_vector_type(2)));

static __device__ __forceinline__ unsigned short f2bf(float f) {
  unsigned int u = __float_as_uint(f);
  u += 0x7fffu + ((u >> 16) & 1u);          // round-to-nearest-even
  return (unsigned short)(u >> 16);
}
static __device__ __forceinline__ unsigned int pack_bf2(float x, float y) {
  return (unsigned int)f2bf(x) | ((unsigned int)f2bf(y) << 16);
}
static __device__ __forceinline__ unsigned int pack_fp8x4(float4 a) {
  unsigned int o = __builtin_amdgcn_cvt_pk_fp8_f32(a.x, a.y, 0u, false);
  o = __builtin_amdgcn_cvt_pk_fp8_f32(a.z, a.w, o, true);
  return o;
}

// ---------- build: partition edges into BOTH CSRs' dst-buckets + bf16 conv ----------
// LDS = 34 KB -> 4 blocks/CU (the round-12 62 KB variant capped at 2 blocks/CU,
// 15% occupancy, and was pure-latency-bound at 5% VALUBusy).
__global__ __launch_bounds__(256) void build_kernel(
    const int* __restrict__ u_idx, const int* __restrict__ i_idx,
    const float* __restrict__ vals,
    int* __restrict__ cursU, int* __restrict__ cursI,
    unsigned int* __restrict__ recsU, unsigned int* __restrict__ recsI,
    unsigned short* __restrict__ dlsU, unsigned short* __restrict__ dlsI,
    const float* __restrict__ embU, unsigned short* __restrict__ ebUb,
    const float* __restrict__ embI, uint2* __restrict__ ebIi1_2,
    int E, int p1blocks) {
  __shared__ int histU[NB], histI[NB], lscanU[NB], lscanI[NB], lbaseU[NB], lbaseI[NB];
  __shared__ unsigned int stageU[T1], stageI[T1];
  __shared__ unsigned short dlstU[T1], dlstI[T1];
  __shared__ unsigned char bktU[T1], bktI[T1];
  int t = threadIdx.x;

  if (blockIdx.x >= p1blocks) {          // ---- conv path ----
    const int n4U = U_CNT * DIM / 4;
    const int nTot = n4U + I_CNT * DIM / 4;
    for (int i = (blockIdx.x - p1blocks) * 256 + t; i < nTot; i += CONVB * 256) {
      if (i < n4U) {
        float4 v = ((const float4*)embU)[i];
        ushort4 o;
        o.x = f2bf(v.x); o.y = f2bf(v.y); o.z = f2bf(v.z); o.w = f2bf(v.w);
        ((ushort4*)ebUb)[i] = o;
      } else {
        int j = i - n4U;
        float4 v = ((const float4*)embI)[j];
        ebIi1_2[2 * j] = make_uint2(pack_bf2(v.x, v.y), pack_bf2(v.z, v.w));
      }
    }
    return;
  }

  // ---- partition path ----
  int tile0 = blockIdx.x * T1;
  int cnt = min(T1, E - tile0);          // always a multiple of 4

  for (int k = t; k < NB; k += 256) { histU[k] = 0; histI[k] = 0; }
  __syncthreads();

  int du[EPT1], di[EPT1]; unsigned int wq[EPT1];
#pragma unroll
  for (int g = 0; g < EPT1 / 4; ++g) {
    int s4 = g * 1024 + t * 4;
    if (s4 < cnt) {
      int e4 = (tile0 + s4) >> 2;
      int4 uu = ((const int4*)u_idx)[e4];
      int4 ii = ((const int4*)i_idx)[e4];
      float4 vv = ((const float4*)vals)[e4];
      du[4*g+0] = uu.x; du[4*g+1] = uu.y; du[4*g+2] = uu.z; du[4*g+3] = uu.w;
      di[4*g+0] = ii.x; di[4*g+1] = ii.y; di[4*g+2] = ii.z; di[4*g+3] = ii.w;
      const float* vp = (const float*)&vv;
#pragma unroll
      for (int j = 0; j < 4; ++j) {
        unsigned int wb = __float_as_uint(vp[j]);
        wq[4*g+j] = ((wb + 0x7fffu + ((wb >> 16) & 1u)) >> 16) & 0x7fffu;
        atomicAdd(&histU[du[4*g+j] >> SHIFT_U], 1);
        atomicAdd(&histI[di[4*g+j] >> SHIFT_I], 1);
      }
    }
  }
  __syncthreads();

  int mU = histU[t], mI = histI[t];
  lbaseU[t] = t * CAP_B + (mU ? atomicAdd(&cursU[t], mU) : 0);
  lbaseI[t] = t * CAP_B + (mI ? atomicAdd(&cursI[t], mI) : 0);
  lscanU[t] = mU; lscanI[t] = mI;
  __syncthreads();
  for (int off = 1; off < NB; off <<= 1) {
    int xu = (t >= off) ? lscanU[t - off] : 0;
    int xi = (t >= off) ? lscanI[t - off] : 0;
    __syncthreads();
    if (t >= off) { lscanU[t] += xu; lscanI[t] += xi; }
    __syncthreads();
  }
  int iU = lscanU[t], iI = lscanI[t];
  __syncthreads();
  lscanU[t] = iU - mU; lscanI[t] = iI - mI;   // exclusive
  histU[t] = 0; histI[t] = 0;                 // reuse as local cursors
  __syncthreads();

#pragma unroll
  for (int g = 0; g < EPT1 / 4; ++g) {
    int s4 = g * 1024 + t * 4;
    if (s4 < cnt) {
#pragma unroll
      for (int j = 0; j < 4; ++j) {
        int k = 4 * g + j;
        int bU = du[k] >> SHIFT_U, bI = di[k] >> SHIFT_I;
        int pU = atomicAdd(&histU[bU], 1);
        int pI = atomicAdd(&histI[bI], 1);
        int sU = lscanU[bU] + pU, sI = lscanI[bI] + pI;
        stageU[sU] = ((unsigned int)di[k] << WQBITS) | wq[k];
        dlstU[sU] = (unsigned short)(du[k] - (bU << SHIFT_U));
        bktU[sU] = (unsigned char)bU;
        stageI[sI] = ((unsigned int)du[k] << WQBITS) | wq[k];
        dlstI[sI] = (unsigned short)(di[k] - (bI << SHIFT_I));
        bktI[sI] = (unsigned char)bI;
      }
    }
  }
  __syncthreads();
  for (int s = t; s < cnt; s += 256) {
    int bU = bktU[s]; int gU = lbaseU[bU] + (s - lscanU[bU]);
    recsU[gU] = stageU[s]; dlsU[gU] = dlstU[s];
    int bI = bktI[s]; int gI = lbaseI[bI] + (s - lscanI[bI]);
    recsI[gI] = stageI[s]; dlsI[gI] = dlstI[s];
  }
}

// ---------- pass 2: order records within each bucket by row; emit (start,end) ----------
__global__ __launch_bounds__(256) void csr_finalize_both(
    const int* __restrict__ cursU, const int* __restrict__ cursI,
    unsigned int* __restrict__ recsU, unsigned int* __restrict__ recsI,
    const unsigned short* __restrict__ dlsU, const unsigned short* __restrict__ dlsI,
    int2* __restrict__ rowseU, int2* __restrict__ rowseI, int nbU) {
  __shared__ int rhist[512];
  __shared__ int rscan[512];
  __shared__ int exsc[512];
  __shared__ unsigned int stage[CAP_B];
  int bb = blockIdx.x, t = threadIdx.x;
  const int* curs; unsigned int* recs; const unsigned short* dls; int2* rowse;
  int nrows, shift, b;
  if (bb < nbU) { b = bb; curs = cursU; recs = recsU; dls = dlsU; rowse = rowseU;
                  nrows = U_CNT; shift = SHIFT_U; }
  else          { b = bb - nbU; curs = cursI; recs = recsI; dls = dlsI; rowse = rowseI;
                  nrows = I_CNT; shift = SHIFT_I; }
  int rpb = 1 << shift;
  int start = b * CAP_B;
  int cnt = min(curs[b], CAP_B);
  int rowbase = b << shift;

  for (int k = t; k < rpb; k += 256) rhist[k] = 0;
  __syncthreads();
  for (int s = t; s < cnt; s += 256)
    atomicAdd(&rhist[dls[start + s]], 1);
  __syncthreads();

  for (int k = t; k < rpb; k += 256) rscan[k] = rhist[k];
  __syncthreads();
  for (int off = 1; off < rpb; off <<= 1) {
    int i0 = t, i1 = t + 256;
    int v0 = (i0 < rpb && i0 >= off) ? rscan[i0 - off] : 0;
    int v1 = (i1 < rpb && i1 >= off) ? rscan[i1 - off] : 0;
    __syncthreads();
    if (i0 < rpb && i0 >= off) rscan[i0] += v0;
    if (i1 < rpb && i1 >= off) rscan[i1] += v1;
    __syncthreads();
  }
  for (int k = t; k < rpb; k += 256) exsc[k] = rscan[k] - rhist[k];
  __syncthreads();

  for (int k = t; k < rpb; k += 256) {
    int r = rowbase + k;
    if (r < nrows) rowse[r] = make_int2(start + exsc[k], start + rscan[k]);
  }

  for (int k = t; k < rpb; k += 256) rhist[k] = 0;  // reuse as cursor
  __syncthreads();
  for (int s = t; s < cnt; s += 256) {
    unsigned int rc = recs[start + s];
    int dl = dls[start + s];
    int pos = atomicAdd(&rhist[dl], 1);
    stage[exsc[dl] + pos] = rc;
  }
  __syncthreads();
  for (int s = t; s < cnt; s += 256) recs[start + s] = stage[s];
}

// ---------- gather cores (quarter-wave: sub = lane&15, q = lane>>4) ----------

// single bf16 gather (row = 16 x 8B)
template <int CHUNK>
static __device__ __forceinline__ float4 gather_bf16(
    const unsigned short* __restrict__ sb,
    const unsigned int* __restrict__ recs,
    int start, int end, int sub, int q) {
  const uint2* s64 = (const uint2*)sb;
  constexpr int K = CHUNK / 4;
  float a0 = 0.f, a1 = 0.f, a2 = 0.f, a3 = 0.f;
  for (int p = start; p < end; p += CHUNK) {
    unsigned int r[K]; uint2 v[K];
#pragma unroll
    for (int k = 0; k < K; ++k) {
      int idx = p + 4 * k + q;
      r[k] = (idx < end) ? recs[idx] : 0u;
    }
#pragma unroll
    for (int k = 0; k < K; ++k)
      v[k] = s64[(size_t)(r[k] >> WQBITS) * 16 + sub];
#pragma unroll
    for (int k = 0; k < K; ++k) {
      float w = __uint_as_float((r[k] & 0x7fffu) << 16);
      a0 += w * __uint_as_float(v[k].x << 16);
      a1 += w * __uint_as_float(v[k].x & 0xffff0000u);
      a2 += w * __uint_as_float(v[k].y << 16);
      a3 += w * __uint_as_float(v[k].y & 0xffff0000u);
    }
  }
  a0 += __shfl_xor(a0, 16); a0 += __shfl_xor(a0, 32);
  a1 += __shfl_xor(a1, 16); a1 += __shfl_xor(a1, 32);
  a2 += __shfl_xor(a2, 16); a2 += __shfl_xor(a2, 32);
  a3 += __shfl_xor(a3, 16); a3 += __shfl_xor(a3, 32);
  return make_float4(a0, a1, a2, a3);
}

// dual bf16 gather from the interleaved ebIi1 array: ONE uint4 load per edge-lane.
template <int CHUNK>
static __device__ __forceinline__ void gather_ebIi1_dual(
    const uint4* __restrict__ s128,
    const unsigned int* __restrict__ recs,
    int start, int end, int sub, int q, float4& o1, float4& o2) {
  constexpr int K = CHUNK / 4;
  float a0 = 0.f, a1 = 0.f, a2 = 0.f, a3 = 0.f;
  float b0 = 0.f, b1 = 0.f, b2 = 0.f, b3 = 0.f;
  for (int p = start; p < end; p += CHUNK) {
    unsigned int r[K]; uint4 v[K];
#pragma unroll
    for (int k = 0; k < K; ++k) {
      int idx = p + 4 * k + q;
      r[k] = (idx < end) ? recs[idx] : 0u;
    }
#pragma unroll
    for (int k = 0; k < K; ++k)
      v[k] = s128[(size_t)(r[k] >> WQBITS) * 16 + sub];
#pragma unroll
    for (int k = 0; k < K; ++k) {
      float w = __uint_as_float((r[k] & 0x7fffu) << 16);
      a0 += w * __uint_as_float(v[k].x << 16);
      a1 += w * __uint_as_float(v[k].x & 0xffff0000u);
      a2 += w * __uint_as_float(v[k].y << 16);
      a3 += w * __uint_as_float(v[k].y & 0xffff0000u);
      b0 += w * __uint_as_float(v[k].z << 16);
      b1 += w * __uint_as_float(v[k].z & 0xffff0000u);
      b2 += w * __uint_as_float(v[k].w << 16);
      b3 += w * __uint_as_float(v[k].w & 0xffff0000u);
    }
  }
  a0 += __shfl_xor(a0, 16); a0 += __shfl_xor(a0, 32);
  a1 += __shfl_xor(a1, 16); a1 += __shfl_xor(a1, 32);
  a2 += __shfl_xor(a2, 16); a2 += __shfl_xor(a2, 32);
  a3 += __shfl_xor(a3, 16); a3 += __shfl_xor(a3, 32);
  b0 += __shfl_xor(b0, 16); b0 += __shfl_xor(b0, 32);
  b1 += __shfl_xor(b1, 16); b1 += __shfl_xor(b1, 32);
  b2 += __shfl_xor(b2, 16); b2 += __shfl_xor(b2, 32);
  b3 += __shfl_xor(b3, 16); b3 += __shfl_xor(b3, 32);
  o1 = make_float4(a0, a1, a2, a3);
  o2 = make_float4(b0, b1, b2, b3);
}

// dual fp8 gather from word-interleaved u12: lane loads uint2 = (u1w, u2w).
template <int CHUNK>
static __device__ __forceinline__ void gather_fp8_dual2(
    const uint2* __restrict__ u12,
    const unsigned int* __restrict__ recs,
    int start, int end, int sub, int q, float4& o1, float4& o2) {
  constexpr int K = CHUNK / 4;
  float a0 = 0.f, a1 = 0.f, a2 = 0.f, a3 = 0.f;
  float b0 = 0.f, b1 = 0.f, b2 = 0.f, b3 = 0.f;
  for (int p = start; p < end; p += CHUNK) {
    unsigned int r[K]; uint2 v[K];
#pragma unroll
    for (int k = 0; k < K; ++k) {
      int idx = p + 4 * k + q;
      r[k] = (idx < end) ? recs[idx] : 0u;
    }
#pragma unroll
    for (int k = 0; k < K; ++k)
      v[k] = u12[(size_t)(r[k] >> WQBITS) * 16 + sub];
#pragma unroll
    for (int k = 0; k < K; ++k) {
      float w = __uint_as_float((r[k] & 0x7fffu) << 16);
      floatx2 lo = __builtin_amdgcn_cvt_pk_f32_fp8(v[k].x, false);
      floatx2 hi = __builtin_amdgcn_cvt_pk_f32_fp8(v[k].x, true);
      a0 += w * lo.x; a1 += w * lo.y; a2 += w * hi.x; a3 += w * hi.y;
      floatx2 lo2 = __builtin_amdgcn_cvt_pk_f32_fp8(v[k].y, false);
      floatx2 hi2 = __builtin_amdgcn_cvt_pk_f32_fp8(v[k].y, true);
      b0 += w * lo2.x; b1 += w * lo2.y; b2 += w * hi2.x; b3 += w * hi2.y;
    }
  }
  a0 += __shfl_xor(a0, 16); a0 += __shfl_xor(a0, 32);
  a1 += __shfl_xor(a1, 16); a1 += __shfl_xor(a1, 32);
  a2 += __shfl_xor(a2, 16); a2 += __shfl_xor(a2, 32);
  a3 += __shfl_xor(a3, 16); a3 += __shfl_xor(a3, 32);
  b0 += __shfl_xor(b0, 16); b0 += __shfl_xor(b0, 32);
  b1 += __shfl_xor(b1, 16); b1 += __shfl_xor(b1, 32);
  b2 += __shfl_xor(b2, 16); b2 += __shfl_xor(b2, 32);
  b3 += __shfl_xor(b3, 16); b3 += __shfl_xor(b3, 32);
  o1 = make_float4(a0, a1, a2, a3);
  o2 = make_float4(b0, b1, b2, b3);
}

// k1: i1(bf16) = spmm_iu(ebU) -> .zw halves of ebIi1   [I rows]
__global__ __launch_bounds__(256) void hop1i_kernel(
    const unsigned short* __restrict__ ebU,
    const unsigned int* __restrict__ recsI, const int2* __restrict__ rowseI,
    uint2* __restrict__ ebIi1_2) {
  int gw = (blockIdx.x * 256 + threadIdx.x) >> 6;
  int lane = threadIdx.x & 63;
  int sub = lane & 15, q = lane >> 4;
  if (gw >= I_CNT) return;
  int2 se = rowseI[gw];
  float4 a = gather_bf16<32>(ebU, recsI, se.x, se.y, sub, q);
  if (q == 0)
    ebIi1_2[2 * ((size_t)gw * 16 + sub) + 1] =
        make_uint2(pack_bf2(a.x, a.y), pack_bf2(a.z, a.w));
}

// k2: dual gather over recsU from interleaved ebIi1: u1 = g(ebI), u2 = g(i1).
__global__ __launch_bounds__(256) void hop1u_kernel(
    const uint4* __restrict__ ebIi1,
    const unsigned int* __restrict__ recsU, const int2* __restrict__ rowseU,
    uint2* __restrict__ u12) {
  int gw = (blockIdx.x * 256 + threadIdx.x) >> 6;
  int lane = threadIdx.x & 63;
  int sub = lane & 15, q = lane >> 4;
  if (gw >= U_CNT) return;
  int2 se = rowseU[gw];
  float4 a, b;
  gather_ebIi1_dual<16>(ebIi1, recsU, se.x, se.y, sub, q, a, b);
  if (q == 0)
    u12[(size_t)gw * 16 + sub] = make_uint2(pack_fp8x4(a), pack_fp8x4(b));
}

// k3: out = e_item + 0.5*i1 + (1/3)*spmm_iu(u1) + 0.25*spmm_iu(u2)
__global__ __launch_bounds__(256) void hop2b_kernel(
    const uint4* __restrict__ ebIi1, const uint2* __restrict__ u12,
    const unsigned int* __restrict__ recsI, const int2* __restrict__ rowseI,
    const float* __restrict__ e_item, float* __restrict__ out) {
  int gw = (blockIdx.x * 256 + threadIdx.x) >> 6;
  int lane = threadIdx.x & 63;
  int sub = lane & 15, q = lane >> 4;
  if (gw >= I_CNT) return;
  int2 se = rowseI[gw];
  float4 a, b;
  gather_fp8_dual2<32>(u12, recsI, se.x, se.y, sub, q, a, b);
  if (q == 0) {
    size_t idx = (size_t)gw * 16 + sub;
    float4 e = ((const float4*)e_item)[idx];
    uint4 t4 = ebIi1[idx];                      // .zw = i1 bf16x4
    const float c1 = 0.5f, c2 = (float)(1.0 / 3.0), c3 = 0.25f;
    float4 o;
    o.x = e.x + c1 * __uint_as_float(t4.z << 16)         + c2 * a.x + c3 * b.x;
    o.y = e.y + c1 * __uint_as_float(t4.z & 0xffff0000u) + c2 * a.y + c3 * b.y;
    o.z = e.z + c1 * __uint_as_float(t4.w << 16)         + c2 * a.z + c3 * b.z;
    o.w = e.w + c1 * __uint_as_float(t4.w & 0xffff0000u) + c2 * a.w + c3 * b.w;
    ((float4*)out)[idx] = o;
  }
}

extern "C" void kernel_launch(void* const* d_in, const int* in_sizes, int n_in,
                              void* d_out, int out_size, void* d_ws, size_t ws_size,
                              hipStream_t stream) {
  const float* embed_user = (const float*)d_in[0];  // [U, D]
  const float* embed_item = (const float*)d_in[1];  // [I, D]
  const float* edge_vals  = (const float*)d_in[2];  // [E]
  const int*   u_idx      = (const int*)d_in[3];    // [E]
  const int*   i_idx      = (const int*)d_in[4];    // [E]
  float* out = (float*)d_out;                       // [I, D]

  auto align256 = [](size_t x) { return (x + 255) & ~(size_t)255; };
  char* ws = (char*)d_ws;
  size_t off = 0;
  const size_t capRecs = (size_t)NB * CAP_B;                          // 2,097,152
  const size_t uHalf = (size_t)U_CNT * DIM * sizeof(unsigned short);  // 12.8 MB
  const size_t iIntl = (size_t)I_CNT * 16 * sizeof(uint4);            // 12.8 MB

  unsigned int* recsU = (unsigned int*)(ws + off); off += align256(capRecs * 4);
  unsigned int* recsI = (unsigned int*)(ws + off); off += align256(capRecs * 4);
  unsigned short* dlU = (unsigned short*)(ws + off); off += align256(capRecs * 2);
  unsigned short* dlI = (unsigned short*)(ws + off); off += align256(capRecs * 2);
  unsigned short* ebUb = (unsigned short*)(ws + off); off += align256(uHalf);
  uint4* ebIi1 = (uint4*)(ws + off); off += align256(iIntl);  // ebI | i1 interleaved
  uint2* u12   = (uint2*)(ws + off); off += align256(uHalf);  // u1 | u2 interleaved fp8
  int2* rowseU = (int2*)(ws + off); off += align256((size_t)U_CNT * sizeof(int2));
  int2* rowseI = (int2*)(ws + off); off += align256((size_t)I_CNT * sizeof(int2));
  int* cursU   = (int*)(ws + off);  off += align256(2 * NB * sizeof(int));
  int* cursI   = cursU + NB;        // contiguous -> single memset
  (void)ws_size;

  dim3 blk(256);

  // ---- build: partition + bf16 conversion in ONE launch ----
  hipMemsetAsync(cursU, 0, 2 * NB * sizeof(int), stream);
  const int p1blocks = (E_CNT + T1 - 1) / T1;  // 611
  build_kernel<<<p1blocks + CONVB, blk, 0, stream>>>(
      u_idx, i_idx, edge_vals, cursU, cursI, recsU, recsI, dlU, dlI,
      embed_user, ebUb, embed_item, (uint2*)ebIi1, E_CNT, p1blocks);

  const int nbValidU = (U_CNT + (1 << SHIFT_U) - 1) >> SHIFT_U;  // 196
  const int nbValidI = (I_CNT + (1 << SHIFT_I) - 1) >> SHIFT_I;  // 196
  csr_finalize_both<<<nbValidU + nbValidI, blk, 0, stream>>>(
      cursU, cursI, recsU, recsI, dlU, dlI, rowseU, rowseI, nbValidU);

  // ---- hops ----
  hop1i_kernel<<<(I_CNT + 3) / 4, blk, 0, stream>>>(ebUb, recsI, rowseI,
                                                    (uint2*)ebIi1);
  hop1u_kernel<<<(U_CNT + 3) / 4, blk, 0, stream>>>(ebIi1, recsU, rowseU, u12);
  hop2b_kernel<<<(I_CNT + 3) / 4, blk, 0, stream>>>(ebIi1, u12, recsI, rowseI,
                                                    embed_item, out);
}

// Round 14
// 155.278 us; speedup vs baseline: 1.0068x; 1.0068x over previous
//
#include <hip/hip_runtime.h>

#define U_CNT 100000
#define I_CNT 50000
#define DIM   64
#define E_CNT 1250000

#define NB      256   // buckets per CSR
#define SHIFT_U 9     // 512 rows/bucket (U)
#define SHIFT_I 8     // 256 rows/bucket (I)
#define T1      4096  // partition tile (edges per block)
#define EPT1    16
#define CAP_B   8192  // fixed capacity per bucket (mean 6400, +22 sigma)
#define WQBITS  15    // record = (src << 15) | top15-of-fp32-weight (sign-less bf16)
#define CONVB   1024  // conv blocks appended to the build launch

typedef float floatx2 __attribute__((ext_vector_type(2)));

static __device__ __forceinline__ unsigned short f2bf(float f) {
  unsigned int u = __float_as_uint(f);
  u += 0x7fffu + ((u >> 16) & 1u);          // round-to-nearest-even
  return (unsigned short)(u >> 16);
}
static __device__ __forceinline__ unsigned int pack_bf2(float x, float y) {
  return (unsigned int)f2bf(x) | ((unsigned int)f2bf(y) << 16);
}
static __device__ __forceinline__ unsigned int pack_fp8x4(float4 a) {
  unsigned int o = __builtin_amdgcn_cvt_pk_fp8_f32(a.x, a.y, 0u, false);
  o = __builtin_amdgcn_cvt_pk_fp8_f32(a.z, a.w, o, true);
  return o;
}

// ---------- build: partition edges into BOTH CSRs' dst-buckets + bf16 conv ----------
// Flush is wave-cooperative bucket-major: each wave copies whole bucket chunks
// (contiguous 4B runs) -> coalesced bursts instead of per-lane scattered stores.
__global__ __launch_bounds__(256) void build_kernel(
    const int* __restrict__ u_idx, const int* __restrict__ i_idx,
    const float* __restrict__ vals,
    int* __restrict__ cursU, int* __restrict__ cursI,
    unsigned int* __restrict__ recsU, unsigned int* __restrict__ recsI,
    unsigned short* __restrict__ dlsU, unsigned short* __restrict__ dlsI,
    const float* __restrict__ embU, unsigned short* __restrict__ ebUb,
    const float* __restrict__ embI, uint2* __restrict__ ebIi1_2,
    int E, int p1blocks) {
  __shared__ int histU[NB], histI[NB], lscanU[NB], lscanI[NB], lbaseU[NB], lbaseI[NB];
  __shared__ unsigned int stageU[T1], stageI[T1];
  __shared__ unsigned short dlstU[T1], dlstI[T1];
  int t = threadIdx.x;

  if (blockIdx.x >= p1blocks) {          // ---- conv path ----
    const int n4U = U_CNT * DIM / 4;
    const int nTot = n4U + I_CNT * DIM / 4;
    for (int i = (blockIdx.x - p1blocks) * 256 + t; i < nTot; i += CONVB * 256) {
      if (i < n4U) {
        float4 v = ((const float4*)embU)[i];
        ushort4 o;
        o.x = f2bf(v.x); o.y = f2bf(v.y); o.z = f2bf(v.z); o.w = f2bf(v.w);
        ((ushort4*)ebUb)[i] = o;
      } else {
        int j = i - n4U;
        float4 v = ((const float4*)embI)[j];
        ebIi1_2[2 * j] = make_uint2(pack_bf2(v.x, v.y), pack_bf2(v.z, v.w));
      }
    }
    return;
  }

  // ---- partition path ----
  int tile0 = blockIdx.x * T1;
  int cnt = min(T1, E - tile0);          // always a multiple of 4

  for (int k = t; k < NB; k += 256) { histU[k] = 0; histI[k] = 0; }
  __syncthreads();

  int du[EPT1], di[EPT1]; unsigned int wq[EPT1];
#pragma unroll
  for (int g = 0; g < EPT1 / 4; ++g) {
    int s4 = g * 1024 + t * 4;
    if (s4 < cnt) {
      int e4 = (tile0 + s4) >> 2;
      int4 uu = ((const int4*)u_idx)[e4];
      int4 ii = ((const int4*)i_idx)[e4];
      float4 vv = ((const float4*)vals)[e4];
      du[4*g+0] = uu.x; du[4*g+1] = uu.y; du[4*g+2] = uu.z; du[4*g+3] = uu.w;
      di[4*g+0] = ii.x; di[4*g+1] = ii.y; di[4*g+2] = ii.z; di[4*g+3] = ii.w;
      const float* vp = (const float*)&vv;
#pragma unroll
      for (int j = 0; j < 4; ++j) {
        unsigned int wb = __float_as_uint(vp[j]);
        wq[4*g+j] = ((wb + 0x7fffu + ((wb >> 16) & 1u)) >> 16) & 0x7fffu;
        atomicAdd(&histU[du[4*g+j] >> SHIFT_U], 1);
        atomicAdd(&histI[di[4*g+j] >> SHIFT_I], 1);
      }
    }
  }
  __syncthreads();

  int mU = histU[t], mI = histI[t];
  lbaseU[t] = t * CAP_B + (mU ? atomicAdd(&cursU[t], mU) : 0);
  lbaseI[t] = t * CAP_B + (mI ? atomicAdd(&cursI[t], mI) : 0);
  lscanU[t] = mU; lscanI[t] = mI;
  __syncthreads();
  for (int off = 1; off < NB; off <<= 1) {
    int xu = (t >= off) ? lscanU[t - off] : 0;
    int xi = (t >= off) ? lscanI[t - off] : 0;
    __syncthreads();
    if (t >= off) { lscanU[t] += xu; lscanI[t] += xi; }
    __syncthreads();
  }
  int iU = lscanU[t], iI = lscanI[t];
  __syncthreads();
  lscanU[t] = iU - mU; lscanI[t] = iI - mI;   // exclusive
  histU[t] = 0; histI[t] = 0;                 // reuse as local cursors
  __syncthreads();

#pragma unroll
  for (int g = 0; g < EPT1 / 4; ++g) {
    int s4 = g * 1024 + t * 4;
    if (s4 < cnt) {
#pragma unroll
      for (int j = 0; j < 4; ++j) {
        int k = 4 * g + j;
        int bU = du[k] >> SHIFT_U, bI = di[k] >> SHIFT_I;
        int pU = atomicAdd(&histU[bU], 1);
        int pI = atomicAdd(&histI[bI], 1);
        int sU = lscanU[bU] + pU, sI = lscanI[bI] + pI;
        stageU[sU] = ((unsigned int)di[k] << WQBITS) | wq[k];
        dlstU[sU] = (unsigned short)(du[k] - (bU << SHIFT_U));
        stageI[sI] = ((unsigned int)du[k] << WQBITS) | wq[k];
        dlstI[sI] = (unsigned short)(di[k] - (bI << SHIFT_I));
      }
    }
  }
  __syncthreads();

  // ---- wave-cooperative bucket-major flush ----
  // histU[b]/histI[b] now hold each bucket's record count (local cursor end).
  int wid = t >> 6, lane = t & 63;
  for (int b = wid; b < NB; b += 4) {
    int cU = histU[b], sU0 = lscanU[b], gU0 = lbaseU[b];
    for (int j = lane; j < cU; j += 64) {
      recsU[gU0 + j] = stageU[sU0 + j];
      dlsU[gU0 + j]  = dlstU[sU0 + j];
    }
    int cI = histI[b], sI0 = lscanI[b], gI0 = lbaseI[b];
    for (int j = lane; j < cI; j += 64) {
      recsI[gI0 + j] = stageI[sI0 + j];
      dlsI[gI0 + j]  = dlstI[sI0 + j];
    }
  }
}

// ---------- pass 2: order records within each bucket by row; emit (start,end) ----------
__global__ __launch_bounds__(256) void csr_finalize_both(
    const int* __restrict__ cursU, const int* __restrict__ cursI,
    unsigned int* __restrict__ recsU, unsigned int* __restrict__ recsI,
    const unsigned short* __restrict__ dlsU, const unsigned short* __restrict__ dlsI,
    int2* __restrict__ rowseU, int2* __restrict__ rowseI, int nbU) {
  __shared__ int rhist[512];
  __shared__ int rscan[512];
  __shared__ int exsc[512];
  __shared__ unsigned int stage[CAP_B];
  int bb = blockIdx.x, t = threadIdx.x;
  const int* curs; unsigned int* recs; const unsigned short* dls; int2* rowse;
  int nrows, shift, b;
  if (bb < nbU) { b = bb; curs = cursU; recs = recsU; dls = dlsU; rowse = rowseU;
                  nrows = U_CNT; shift = SHIFT_U; }
  else          { b = bb - nbU; curs = cursI; recs = recsI; dls = dlsI; rowse = rowseI;
                  nrows = I_CNT; shift = SHIFT_I; }
  int rpb = 1 << shift;
  int start = b * CAP_B;
  int cnt = min(curs[b], CAP_B);
  int rowbase = b << shift;

  for (int k = t; k < rpb; k += 256) rhist[k] = 0;
  __syncthreads();
  for (int s = t; s < cnt; s += 256)
    atomicAdd(&rhist[dls[start + s]], 1);
  __syncthreads();

  for (int k = t; k < rpb; k += 256) rscan[k] = rhist[k];
  __syncthreads();
  for (int off = 1; off < rpb; off <<= 1) {
    int i0 = t, i1 = t + 256;
    int v0 = (i0 < rpb && i0 >= off) ? rscan[i0 - off] : 0;
    int v1 = (i1 < rpb && i1 >= off) ? rscan[i1 - off] : 0;
    __syncthreads();
    if (i0 < rpb && i0 >= off) rscan[i0] += v0;
    if (i1 < rpb && i1 >= off) rscan[i1] += v1;
    __syncthreads();
  }
  for (int k = t; k < rpb; k += 256) exsc[k] = rscan[k] - rhist[k];
  __syncthreads();

  for (int k = t; k < rpb; k += 256) {
    int r = rowbase + k;
    if (r < nrows) rowse[r] = make_int2(start + exsc[k], start + rscan[k]);
  }

  for (int k = t; k < rpb; k += 256) rhist[k] = 0;  // reuse as cursor
  __syncthreads();
  for (int s = t; s < cnt; s += 256) {
    unsigned int rc = recs[start + s];
    int dl = dls[start + s];
    int pos = atomicAdd(&rhist[dl], 1);
    stage[exsc[dl] + pos] = rc;
  }
  __syncthreads();
  for (int s = t; s < cnt; s += 256) recs[start + s] = stage[s];
}

// ---------- gather cores (quarter-wave: sub = lane&15, q = lane>>4) ----------

// single bf16 gather (row = 16 x 8B)
template <int CHUNK>
static __device__ __forceinline__ float4 gather_bf16(
    const unsigned short* __restrict__ sb,
    const unsigned int* __restrict__ recs,
    int start, int end, int sub, int q) {
  const uint2* s64 = (const uint2*)sb;
  constexpr int K = CHUNK / 4;
  float a0 = 0.f, a1 = 0.f, a2 = 0.f, a3 = 0.f;
  for (int p = start; p < end; p += CHUNK) {
    unsigned int r[K]; uint2 v[K];
#pragma unroll
    for (int k = 0; k < K; ++k) {
      int idx = p + 4 * k + q;
      r[k] = (idx < end) ? recs[idx] : 0u;
    }
#pragma unroll
    for (int k = 0; k < K; ++k)
      v[k] = s64[(size_t)(r[k] >> WQBITS) * 16 + sub];
#pragma unroll
    for (int k = 0; k < K; ++k) {
      float w = __uint_as_float((r[k] & 0x7fffu) << 16);
      a0 += w * __uint_as_float(v[k].x << 16);
      a1 += w * __uint_as_float(v[k].x & 0xffff0000u);
      a2 += w * __uint_as_float(v[k].y << 16);
      a3 += w * __uint_as_float(v[k].y & 0xffff0000u);
    }
  }
  a0 += __shfl_xor(a0, 16); a0 += __shfl_xor(a0, 32);
  a1 += __shfl_xor(a1, 16); a1 += __shfl_xor(a1, 32);
  a2 += __shfl_xor(a2, 16); a2 += __shfl_xor(a2, 32);
  a3 += __shfl_xor(a3, 16); a3 += __shfl_xor(a3, 32);
  return make_float4(a0, a1, a2, a3);
}

// dual bf16 gather from the interleaved ebIi1 array: ONE uint4 load per edge-lane.
template <int CHUNK>
static __device__ __forceinline__ void gather_ebIi1_dual(
    const uint4* __restrict__ s128,
    const unsigned int* __restrict__ recs,
    int start, int end, int sub, int q, float4& o1, float4& o2) {
  constexpr int K = CHUNK / 4;
  float a0 = 0.f, a1 = 0.f, a2 = 0.f, a3 = 0.f;
  float b0 = 0.f, b1 = 0.f, b2 = 0.f, b3 = 0.f;
  for (int p = start; p < end; p += CHUNK) {
    unsigned int r[K]; uint4 v[K];
#pragma unroll
    for (int k = 0; k < K; ++k) {
      int idx = p + 4 * k + q;
      r[k] = (idx < end) ? recs[idx] : 0u;
    }
#pragma unroll
    for (int k = 0; k < K; ++k)
      v[k] = s128[(size_t)(r[k] >> WQBITS) * 16 + sub];
#pragma unroll
    for (int k = 0; k < K; ++k) {
      float w = __uint_as_float((r[k] & 0x7fffu) << 16);
      a0 += w * __uint_as_float(v[k].x << 16);
      a1 += w * __uint_as_float(v[k].x & 0xffff0000u);
      a2 += w * __uint_as_float(v[k].y << 16);
      a3 += w * __uint_as_float(v[k].y & 0xffff0000u);
      b0 += w * __uint_as_float(v[k].z << 16);
      b1 += w * __uint_as_float(v[k].z & 0xffff0000u);
      b2 += w * __uint_as_float(v[k].w << 16);
      b3 += w * __uint_as_float(v[k].w & 0xffff0000u);
    }
  }
  a0 += __shfl_xor(a0, 16); a0 += __shfl_xor(a0, 32);
  a1 += __shfl_xor(a1, 16); a1 += __shfl_xor(a1, 32);
  a2 += __shfl_xor(a2, 16); a2 += __shfl_xor(a2, 32);
  a3 += __shfl_xor(a3, 16); a3 += __shfl_xor(a3, 32);
  b0 += __shfl_xor(b0, 16); b0 += __shfl_xor(b0, 32);
  b1 += __shfl_xor(b1, 16); b1 += __shfl_xor(b1, 32);
  b2 += __shfl_xor(b2, 16); b2 += __shfl_xor(b2, 32);
  b3 += __shfl_xor(b3, 16); b3 += __shfl_xor(b3, 32);
  o1 = make_float4(a0, a1, a2, a3);
  o2 = make_float4(b0, b1, b2, b3);
}

// dual fp8 gather from word-interleaved u12: lane loads uint2 = (u1w, u2w).
template <int CHUNK>
static __device__ __forceinline__ void gather_fp8_dual2(
    const uint2* __restrict__ u12,
    const unsigned int* __restrict__ recs,
    int start, int end, int sub, int q, float4& o1, float4& o2) {
  constexpr int K = CHUNK / 4;
  float a0 = 0.f, a1 = 0.f, a2 = 0.f, a3 = 0.f;
  float b0 = 0.f, b1 = 0.f, b2 = 0.f, b3 = 0.f;
  for (int p = start; p < end; p += CHUNK) {
    unsigned int r[K]; uint2 v[K];
#pragma unroll
    for (int k = 0; k < K; ++k) {
      int idx = p + 4 * k + q;
      r[k] = (idx < end) ? recs[idx] : 0u;
    }
#pragma unroll
    for (int k = 0; k < K; ++k)
      v[k] = u12[(size_t)(r[k] >> WQBITS) * 16 + sub];
#pragma unroll
    for (int k = 0; k < K; ++k) {
      float w = __uint_as_float((r[k] & 0x7fffu) << 16);
      floatx2 lo = __builtin_amdgcn_cvt_pk_f32_fp8(v[k].x, false);
      floatx2 hi = __builtin_amdgcn_cvt_pk_f32_fp8(v[k].x, true);
      a0 += w * lo.x; a1 += w * lo.y; a2 += w * hi.x; a3 += w * hi.y;
      floatx2 lo2 = __builtin_amdgcn_cvt_pk_f32_fp8(v[k].y, false);
      floatx2 hi2 = __builtin_amdgcn_cvt_pk_f32_fp8(v[k].y, true);
      b0 += w * lo2.x; b1 += w * lo2.y; b2 += w * hi2.x; b3 += w * hi2.y;
    }
  }
  a0 += __shfl_xor(a0, 16); a0 += __shfl_xor(a0, 32);
  a1 += __shfl_xor(a1, 16); a1 += __shfl_xor(a1, 32);
  a2 += __shfl_xor(a2, 16); a2 += __shfl_xor(a2, 32);
  a3 += __shfl_xor(a3, 16); a3 += __shfl_xor(a3, 32);
  b0 += __shfl_xor(b0, 16); b0 += __shfl_xor(b0, 32);
  b1 += __shfl_xor(b1, 16); b1 += __shfl_xor(b1, 32);
  b2 += __shfl_xor(b2, 16); b2 += __shfl_xor(b2, 32);
  b3 += __shfl_xor(b3, 16); b3 += __shfl_xor(b3, 32);
  o1 = make_float4(a0, a1, a2, a3);
  o2 = make_float4(b0, b1, b2, b3);
}

// k1: i1(bf16) = spmm_iu(ebU) -> .zw halves of ebIi1   [I rows]
__global__ __launch_bounds__(256) void hop1i_kernel(
    const unsigned short* __restrict__ ebU,
    const unsigned int* __restrict__ recsI, const int2* __restrict__ rowseI,
    uint2* __restrict__ ebIi1_2) {
  int gw = (blockIdx.x * 256 + threadIdx.x) >> 6;
  int lane = threadIdx.x & 63;
  int sub = lane & 15, q = lane >> 4;
  if (gw >= I_CNT) return;
  int2 se = rowseI[gw];
  float4 a = gather_bf16<32>(ebU, recsI, se.x, se.y, sub, q);
  if (q == 0)
    ebIi1_2[2 * ((size_t)gw * 16 + sub) + 1] =
        make_uint2(pack_bf2(a.x, a.y), pack_bf2(a.z, a.w));
}

// k2: dual gather over recsU from interleaved ebIi1: u1 = g(ebI), u2 = g(i1).
__global__ __launch_bounds__(256) void hop1u_kernel(
    const uint4* __restrict__ ebIi1,
    const unsigned int* __restrict__ recsU, const int2* __restrict__ rowseU,
    uint2* __restrict__ u12) {
  int gw = (blockIdx.x * 256 + threadIdx.x) >> 6;
  int lane = threadIdx.x & 63;
  int sub = lane & 15, q = lane >> 4;
  if (gw >= U_CNT) return;
  int2 se = rowseU[gw];
  float4 a, b;
  gather_ebIi1_dual<16>(ebIi1, recsU, se.x, se.y, sub, q, a, b);
  if (q == 0)
    u12[(size_t)gw * 16 + sub] = make_uint2(pack_fp8x4(a), pack_fp8x4(b));
}

// k3: out = e_item + 0.5*i1 + (1/3)*spmm_iu(u1) + 0.25*spmm_iu(u2)
__global__ __launch_bounds__(256) void hop2b_kernel(
    const uint4* __restrict__ ebIi1, const uint2* __restrict__ u12,
    const unsigned int* __restrict__ recsI, const int2* __restrict__ rowseI,
    const float* __restrict__ e_item, float* __restrict__ out) {
  int gw = (blockIdx.x * 256 + threadIdx.x) >> 6;
  int lane = threadIdx.x & 63;
  int sub = lane & 15, q = lane >> 4;
  if (gw >= I_CNT) return;
  int2 se = rowseI[gw];
  float4 a, b;
  gather_fp8_dual2<32>(u12, recsI, se.x, se.y, sub, q, a, b);
  if (q == 0) {
    size_t idx = (size_t)gw * 16 + sub;
    float4 e = ((const float4*)e_item)[idx];
    uint4 t4 = ebIi1[idx];                      // .zw = i1 bf16x4
    const float c1 = 0.5f, c2 = (float)(1.0 / 3.0), c3 = 0.25f;
    float4 o;
    o.x = e.x + c1 * __uint_as_float(t4.z << 16)         + c2 * a.x + c3 * b.x;
    o.y = e.y + c1 * __uint_as_float(t4.z & 0xffff0000u) + c2 * a.y + c3 * b.y;
    o.z = e.z + c1 * __uint_as_float(t4.w << 16)         + c2 * a.z + c3 * b.z;
    o.w = e.w + c1 * __uint_as_float(t4.w & 0xffff0000u) + c2 * a.w + c3 * b.w;
    ((float4*)out)[idx] = o;
  }
}

extern "C" void kernel_launch(void* const* d_in, const int* in_sizes, int n_in,
                              void* d_out, int out_size, void* d_ws, size_t ws_size,
                              hipStream_t stream) {
  const float* embed_user = (const float*)d_in[0];  // [U, D]
  const float* embed_item = (const float*)d_in[1];  // [I, D]
  const float* edge_vals  = (const float*)d_in[2];  // [E]
  const int*   u_idx      = (const int*)d_in[3];    // [E]
  const int*   i_idx      = (const int*)d_in[4];    // [E]
  float* out = (float*)d_out;                       // [I, D]

  auto align256 = [](size_t x) { return (x + 255) & ~(size_t)255; };
  char* ws = (char*)d_ws;
  size_t off = 0;
  const size_t capRecs = (size_t)NB * CAP_B;                          // 2,097,152
  const size_t uHalf = (size_t)U_CNT * DIM * sizeof(unsigned short);  // 12.8 MB
  const size_t iIntl = (size_t)I_CNT * 16 * sizeof(uint4);            // 12.8 MB

  unsigned int* recsU = (unsigned int*)(ws + off); off += align256(capRecs * 4);
  unsigned int* recsI = (unsigned int*)(ws + off); off += align256(capRecs * 4);
  unsigned short* dlU = (unsigned short*)(ws + off); off += align256(capRecs * 2);
  unsigned short* dlI = (unsigned short*)(ws + off); off += align256(capRecs * 2);
  unsigned short* ebUb = (unsigned short*)(ws + off); off += align256(uHalf);
  uint4* ebIi1 = (uint4*)(ws + off); off += align256(iIntl);  // ebI | i1 interleaved
  uint2* u12   = (uint2*)(ws + off); off += align256(uHalf);  // u1 | u2 interleaved fp8
  int2* rowseU = (int2*)(ws + off); off += align256((size_t)U_CNT * sizeof(int2));
  int2* rowseI = (int2*)(ws + off); off += align256((size_t)I_CNT * sizeof(int2));
  int* cursU   = (int*)(ws + off);  off += align256(2 * NB * sizeof(int));
  int* cursI   = cursU + NB;        // contiguous -> single memset
  (void)ws_size;

  dim3 blk(256);

  // ---- build: partition + bf16 conversion in ONE launch ----
  hipMemsetAsync(cursU, 0, 2 * NB * sizeof(int), stream);
  const int p1blocks = (E_CNT + T1 - 1) / T1;  // 306
  build_kernel<<<p1blocks + CONVB, blk, 0, stream>>>(
      u_idx, i_idx, edge_vals, cursU, cursI, recsU, recsI, dlU, dlI,
      embed_user, ebUb, embed_item, (uint2*)ebIi1, E_CNT, p1blocks);

  const int nbValidU = (U_CNT + (1 << SHIFT_U) - 1) >> SHIFT_U;  // 196
  const int nbValidI = (I_CNT + (1 << SHIFT_I) - 1) >> SHIFT_I;  // 196
  csr_finalize_both<<<nbValidU + nbValidI, blk, 0, stream>>>(
      cursU, cursI, recsU, recsI, dlU, dlI, rowseU, rowseI, nbValidU);

  // ---- hops ----
  hop1i_kernel<<<(I_CNT + 3) / 4, blk, 0, stream>>>(ebUb, recsI, rowseI,
                                                    (uint2*)ebIi1);
  hop1u_kernel<<<(U_CNT + 3) / 4, blk, 0, stream>>>(ebIi1, recsU, rowseU, u12);
  hop2b_kernel<<<(I_CNT + 3) / 4, blk, 0, stream>>>(ebIi1, u12, recsI, rowseI,
                                                    embed_item, out);
}

// Round 15
// 147.467 us; speedup vs baseline: 1.0601x; 1.0530x over previous
//
#include <hip/hip_runtime.h>

#define U_CNT 100000
#define I_CNT 50000
#define DIM   64
#define E_CNT 1250000

#define NB      256   // buckets per CSR
#define SHIFT_U 9     // 512 rows/bucket (U)
#define SHIFT_I 8     // 256 rows/bucket (I)
#define T1      4096  // partition tile (edges per block)
#define EPT1    16
#define CAP_B   8192  // fixed capacity per bucket (mean 6400, +22 sigma)
#define WQBITS  15    // record = (src << 15) | top15-of-fp32-weight (sign-less bf16)
#define CONVB   1024  // conv blocks appended to the build launch

typedef float floatx2 __attribute__((ext_vector_type(2)));

static __device__ __forceinline__ unsigned short f2bf(float f) {
  unsigned int u = __float_as_uint(f);
  u += 0x7fffu + ((u >> 16) & 1u);          // round-to-nearest-even
  return (unsigned short)(u >> 16);
}
static __device__ __forceinline__ unsigned int pack_bf2(float x, float y) {
  return (unsigned int)f2bf(x) | ((unsigned int)f2bf(y) << 16);
}
static __device__ __forceinline__ unsigned int pack_fp8x4(float4 a) {
  unsigned int o = __builtin_amdgcn_cvt_pk_fp8_f32(a.x, a.y, 0u, false);
  o = __builtin_amdgcn_cvt_pk_fp8_f32(a.z, a.w, o, true);
  return o;
}

// ---------- build: partition edges into BOTH CSRs' dst-buckets + bf16 conv ----------
// Round-12 configuration: T1=4096, per-lane flush with bkt[] sideband. Two
// alternatives measured and REJECTED: T1=2048 (2x occupancy, slower — not
// occupancy-bound) and wave-cooperative bucket-major flush (same WRITE_SIZE,
// slower — L2 already write-combines the per-lane 4B runs).
__global__ __launch_bounds__(256) void build_kernel(
    const int* __restrict__ u_idx, const int* __restrict__ i_idx,
    const float* __restrict__ vals,
    int* __restrict__ cursU, int* __restrict__ cursI,
    unsigned int* __restrict__ recsU, unsigned int* __restrict__ recsI,
    unsigned short* __restrict__ dlsU, unsigned short* __restrict__ dlsI,
    const float* __restrict__ embU, unsigned short* __restrict__ ebUb,
    const float* __restrict__ embI, uint2* __restrict__ ebIi1_2,
    int E, int p1blocks) {
  __shared__ int histU[NB], histI[NB], lscanU[NB], lscanI[NB], lbaseU[NB], lbaseI[NB];
  __shared__ unsigned int stageU[T1], stageI[T1];
  __shared__ unsigned short dlstU[T1], dlstI[T1];
  __shared__ unsigned char bktU[T1], bktI[T1];
  int t = threadIdx.x;

  if (blockIdx.x >= p1blocks) {          // ---- conv path ----
    const int n4U = U_CNT * DIM / 4;
    const int nTot = n4U + I_CNT * DIM / 4;
    for (int i = (blockIdx.x - p1blocks) * 256 + t; i < nTot; i += CONVB * 256) {
      if (i < n4U) {
        float4 v = ((const float4*)embU)[i];
        ushort4 o;
        o.x = f2bf(v.x); o.y = f2bf(v.y); o.z = f2bf(v.z); o.w = f2bf(v.w);
        ((ushort4*)ebUb)[i] = o;
      } else {
        int j = i - n4U;
        float4 v = ((const float4*)embI)[j];
        ebIi1_2[2 * j] = make_uint2(pack_bf2(v.x, v.y), pack_bf2(v.z, v.w));
      }
    }
    return;
  }

  // ---- partition path ----
  int tile0 = blockIdx.x * T1;
  int cnt = min(T1, E - tile0);          // always a multiple of 4

  for (int k = t; k < NB; k += 256) { histU[k] = 0; histI[k] = 0; }
  __syncthreads();

  int du[EPT1], di[EPT1]; unsigned int wq[EPT1];
#pragma unroll
  for (int g = 0; g < EPT1 / 4; ++g) {
    int s4 = g * 1024 + t * 4;
    if (s4 < cnt) {
      int e4 = (tile0 + s4) >> 2;
      int4 uu = ((const int4*)u_idx)[e4];
      int4 ii = ((const int4*)i_idx)[e4];
      float4 vv = ((const float4*)vals)[e4];
      du[4*g+0] = uu.x; du[4*g+1] = uu.y; du[4*g+2] = uu.z; du[4*g+3] = uu.w;
      di[4*g+0] = ii.x; di[4*g+1] = ii.y; di[4*g+2] = ii.z; di[4*g+3] = ii.w;
      const float* vp = (const float*)&vv;
#pragma unroll
      for (int j = 0; j < 4; ++j) {
        unsigned int wb = __float_as_uint(vp[j]);
        wq[4*g+j] = ((wb + 0x7fffu + ((wb >> 16) & 1u)) >> 16) & 0x7fffu;
        atomicAdd(&histU[du[4*g+j] >> SHIFT_U], 1);
        atomicAdd(&histI[di[4*g+j] >> SHIFT_I], 1);
      }
    }
  }
  __syncthreads();

  int mU = histU[t], mI = histI[t];
  lbaseU[t] = t * CAP_B + (mU ? atomicAdd(&cursU[t], mU) : 0);
  lbaseI[t] = t * CAP_B + (mI ? atomicAdd(&cursI[t], mI) : 0);
  lscanU[t] = mU; lscanI[t] = mI;
  __syncthreads();
  for (int off = 1; off < NB; off <<= 1) {
    int xu = (t >= off) ? lscanU[t - off] : 0;
    int xi = (t >= off) ? lscanI[t - off] : 0;
    __syncthreads();
    if (t >= off) { lscanU[t] += xu; lscanI[t] += xi; }
    __syncthreads();
  }
  int iU = lscanU[t], iI = lscanI[t];
  __syncthreads();
  lscanU[t] = iU - mU; lscanI[t] = iI - mI;   // exclusive
  histU[t] = 0; histI[t] = 0;                 // reuse as local cursors
  __syncthreads();

#pragma unroll
  for (int g = 0; g < EPT1 / 4; ++g) {
    int s4 = g * 1024 + t * 4;
    if (s4 < cnt) {
#pragma unroll
      for (int j = 0; j < 4; ++j) {
        int k = 4 * g + j;
        int bU = du[k] >> SHIFT_U, bI = di[k] >> SHIFT_I;
        int pU = atomicAdd(&histU[bU], 1);
        int pI = atomicAdd(&histI[bI], 1);
        int sU = lscanU[bU] + pU, sI = lscanI[bI] + pI;
        stageU[sU] = ((unsigned int)di[k] << WQBITS) | wq[k];
        dlstU[sU] = (unsigned short)(du[k] - (bU << SHIFT_U));
        bktU[sU] = (unsigned char)bU;
        stageI[sI] = ((unsigned int)du[k] << WQBITS) | wq[k];
        dlstI[sI] = (unsigned short)(di[k] - (bI << SHIFT_I));
        bktI[sI] = (unsigned char)bI;
      }
    }
  }
  __syncthreads();
  for (int s = t; s < cnt; s += 256) {
    int bU = bktU[s]; int gU = lbaseU[bU] + (s - lscanU[bU]);
    recsU[gU] = stageU[s]; dlsU[gU] = dlstU[s];
    int bI = bktI[s]; int gI = lbaseI[bI] + (s - lscanI[bI]);
    recsI[gI] = stageI[s]; dlsI[gI] = dlstI[s];
  }
}

// ---------- pass 2: order records within each bucket by row; emit (start,end) ----------
__global__ __launch_bounds__(256) void csr_finalize_both(
    const int* __restrict__ cursU, const int* __restrict__ cursI,
    unsigned int* __restrict__ recsU, unsigned int* __restrict__ recsI,
    const unsigned short* __restrict__ dlsU, const unsigned short* __restrict__ dlsI,
    int2* __restrict__ rowseU, int2* __restrict__ rowseI, int nbU) {
  __shared__ int rhist[512];
  __shared__ int rscan[512];
  __shared__ int exsc[512];
  __shared__ unsigned int stage[CAP_B];
  int bb = blockIdx.x, t = threadIdx.x;
  const int* curs; unsigned int* recs; const unsigned short* dls; int2* rowse;
  int nrows, shift, b;
  if (bb < nbU) { b = bb; curs = cursU; recs = recsU; dls = dlsU; rowse = rowseU;
                  nrows = U_CNT; shift = SHIFT_U; }
  else          { b = bb - nbU; curs = cursI; recs = recsI; dls = dlsI; rowse = rowseI;
                  nrows = I_CNT; shift = SHIFT_I; }
  int rpb = 1 << shift;
  int start = b * CAP_B;
  int cnt = min(curs[b], CAP_B);
  int rowbase = b << shift;

  for (int k = t; k < rpb; k += 256) rhist[k] = 0;
  __syncthreads();
  for (int s = t; s < cnt; s += 256)
    atomicAdd(&rhist[dls[start + s]], 1);
  __syncthreads();

  for (int k = t; k < rpb; k += 256) rscan[k] = rhist[k];
  __syncthreads();
  for (int off = 1; off < rpb; off <<= 1) {
    int i0 = t, i1 = t + 256;
    int v0 = (i0 < rpb && i0 >= off) ? rscan[i0 - off] : 0;
    int v1 = (i1 < rpb && i1 >= off) ? rscan[i1 - off] : 0;
    __syncthreads();
    if (i0 < rpb && i0 >= off) rscan[i0] += v0;
    if (i1 < rpb && i1 >= off) rscan[i1] += v1;
    __syncthreads();
  }
  for (int k = t; k < rpb; k += 256) exsc[k] = rscan[k] - rhist[k];
  __syncthreads();

  for (int k = t; k < rpb; k += 256) {
    int r = rowbase + k;
    if (r < nrows) rowse[r] = make_int2(start + exsc[k], start + rscan[k]);
  }

  for (int k = t; k < rpb; k += 256) rhist[k] = 0;  // reuse as cursor
  __syncthreads();
  for (int s = t; s < cnt; s += 256) {
    unsigned int rc = recs[start + s];
    int dl = dls[start + s];
    int pos = atomicAdd(&rhist[dl], 1);
    stage[exsc[dl] + pos] = rc;
  }
  __syncthreads();
  for (int s = t; s < cnt; s += 256) recs[start + s] = stage[s];
}

// ---------- gather cores (quarter-wave: sub = lane&15, q = lane>>4) ----------

// single bf16 gather (row = 16 x 8B)
template <int CHUNK>
static __device__ __forceinline__ float4 gather_bf16(
    const unsigned short* __restrict__ sb,
    const unsigned int* __restrict__ recs,
    int start, int end, int sub, int q) {
  const uint2* s64 = (const uint2*)sb;
  constexpr int K = CHUNK / 4;
  float a0 = 0.f, a1 = 0.f, a2 = 0.f, a3 = 0.f;
  for (int p = start; p < end; p += CHUNK) {
    unsigned int r[K]; uint2 v[K];
#pragma unroll
    for (int k = 0; k < K; ++k) {
      int idx = p + 4 * k + q;
      r[k] = (idx < end) ? recs[idx] : 0u;
    }
#pragma unroll
    for (int k = 0; k < K; ++k)
      v[k] = s64[(size_t)(r[k] >> WQBITS) * 16 + sub];
#pragma unroll
    for (int k = 0; k < K; ++k) {
      float w = __uint_as_float((r[k] & 0x7fffu) << 16);
      a0 += w * __uint_as_float(v[k].x << 16);
      a1 += w * __uint_as_float(v[k].x & 0xffff0000u);
      a2 += w * __uint_as_float(v[k].y << 16);
      a3 += w * __uint_as_float(v[k].y & 0xffff0000u);
    }
  }
  a0 += __shfl_xor(a0, 16); a0 += __shfl_xor(a0, 32);
  a1 += __shfl_xor(a1, 16); a1 += __shfl_xor(a1, 32);
  a2 += __shfl_xor(a2, 16); a2 += __shfl_xor(a2, 32);
  a3 += __shfl_xor(a3, 16); a3 += __shfl_xor(a3, 32);
  return make_float4(a0, a1, a2, a3);
}

// dual bf16 gather from the interleaved ebIi1 array: ONE uint4 load per edge-lane.
template <int CHUNK>
static __device__ __forceinline__ void gather_ebIi1_dual(
    const uint4* __restrict__ s128,
    const unsigned int* __restrict__ recs,
    int start, int end, int sub, int q, float4& o1, float4& o2) {
  constexpr int K = CHUNK / 4;
  float a0 = 0.f, a1 = 0.f, a2 = 0.f, a3 = 0.f;
  float b0 = 0.f, b1 = 0.f, b2 = 0.f, b3 = 0.f;
  for (int p = start; p < end; p += CHUNK) {
    unsigned int r[K]; uint4 v[K];
#pragma unroll
    for (int k = 0; k < K; ++k) {
      int idx = p + 4 * k + q;
      r[k] = (idx < end) ? recs[idx] : 0u;
    }
#pragma unroll
    for (int k = 0; k < K; ++k)
      v[k] = s128[(size_t)(r[k] >> WQBITS) * 16 + sub];
#pragma unroll
    for (int k = 0; k < K; ++k) {
      float w = __uint_as_float((r[k] & 0x7fffu) << 16);
      a0 += w * __uint_as_float(v[k].x << 16);
      a1 += w * __uint_as_float(v[k].x & 0xffff0000u);
      a2 += w * __uint_as_float(v[k].y << 16);
      a3 += w * __uint_as_float(v[k].y & 0xffff0000u);
      b0 += w * __uint_as_float(v[k].z << 16);
      b1 += w * __uint_as_float(v[k].z & 0xffff0000u);
      b2 += w * __uint_as_float(v[k].w << 16);
      b3 += w * __uint_as_float(v[k].w & 0xffff0000u);
    }
  }
  a0 += __shfl_xor(a0, 16); a0 += __shfl_xor(a0, 32);
  a1 += __shfl_xor(a1, 16); a1 += __shfl_xor(a1, 32);
  a2 += __shfl_xor(a2, 16); a2 += __shfl_xor(a2, 32);
  a3 += __shfl_xor(a3, 16); a3 += __shfl_xor(a3, 32);
  b0 += __shfl_xor(b0, 16); b0 += __shfl_xor(b0, 32);
  b1 += __shfl_xor(b1, 16); b1 += __shfl_xor(b1, 32);
  b2 += __shfl_xor(b2, 16); b2 += __shfl_xor(b2, 32);
  b3 += __shfl_xor(b3, 16); b3 += __shfl_xor(b3, 32);
  o1 = make_float4(a0, a1, a2, a3);
  o2 = make_float4(b0, b1, b2, b3);
}

// dual fp8 gather from word-interleaved u12: lane loads uint2 = (u1w, u2w).
template <int CHUNK>
static __device__ __forceinline__ void gather_fp8_dual2(
    const uint2* __restrict__ u12,
    const unsigned int* __restrict__ recs,
    int start, int end, int sub, int q, float4& o1, float4& o2) {
  constexpr int K = CHUNK / 4;
  float a0 = 0.f, a1 = 0.f, a2 = 0.f, a3 = 0.f;
  float b0 = 0.f, b1 = 0.f, b2 = 0.f, b3 = 0.f;
  for (int p = start; p < end; p += CHUNK) {
    unsigned int r[K]; uint2 v[K];
#pragma unroll
    for (int k = 0; k < K; ++k) {
      int idx = p + 4 * k + q;
      r[k] = (idx < end) ? recs[idx] : 0u;
    }
#pragma unroll
    for (int k = 0; k < K; ++k)
      v[k] = u12[(size_t)(r[k] >> WQBITS) * 16 + sub];
#pragma unroll
    for (int k = 0; k < K; ++k) {
      float w = __uint_as_float((r[k] & 0x7fffu) << 16);
      floatx2 lo = __builtin_amdgcn_cvt_pk_f32_fp8(v[k].x, false);
      floatx2 hi = __builtin_amdgcn_cvt_pk_f32_fp8(v[k].x, true);
      a0 += w * lo.x; a1 += w * lo.y; a2 += w * hi.x; a3 += w * hi.y;
      floatx2 lo2 = __builtin_amdgcn_cvt_pk_f32_fp8(v[k].y, false);
      floatx2 hi2 = __builtin_amdgcn_cvt_pk_f32_fp8(v[k].y, true);
      b0 += w * lo2.x; b1 += w * lo2.y; b2 += w * hi2.x; b3 += w * hi2.y;
    }
  }
  a0 += __shfl_xor(a0, 16); a0 += __shfl_xor(a0, 32);
  a1 += __shfl_xor(a1, 16); a1 += __shfl_xor(a1, 32);
  a2 += __shfl_xor(a2, 16); a2 += __shfl_xor(a2, 32);
  a3 += __shfl_xor(a3, 16); a3 += __shfl_xor(a3, 32);
  b0 += __shfl_xor(b0, 16); b0 += __shfl_xor(b0, 32);
  b1 += __shfl_xor(b1, 16); b1 += __shfl_xor(b1, 32);
  b2 += __shfl_xor(b2, 16); b2 += __shfl_xor(b2, 32);
  b3 += __shfl_xor(b3, 16); b3 += __shfl_xor(b3, 32);
  o1 = make_float4(a0, a1, a2, a3);
  o2 = make_float4(b0, b1, b2, b3);
}

// k1: i1(bf16) = spmm_iu(ebU) -> .zw halves of ebIi1   [I rows]
__global__ __launch_bounds__(256) void hop1i_kernel(
    const unsigned short* __restrict__ ebU,
    const unsigned int* __restrict__ recsI, const int2* __restrict__ rowseI,
    uint2* __restrict__ ebIi1_2) {
  int gw = (blockIdx.x * 256 + threadIdx.x) >> 6;
  int lane = threadIdx.x & 63;
  int sub = lane & 15, q = lane >> 4;
  if (gw >= I_CNT) return;
  int2 se = rowseI[gw];
  float4 a = gather_bf16<32>(ebU, recsI, se.x, se.y, sub, q);
  if (q == 0)
    ebIi1_2[2 * ((size_t)gw * 16 + sub) + 1] =
        make_uint2(pack_bf2(a.x, a.y), pack_bf2(a.z, a.w));
}

// k2: dual gather over recsU from interleaved ebIi1: u1 = g(ebI), u2 = g(i1).
__global__ __launch_bounds__(256) void hop1u_kernel(
    const uint4* __restrict__ ebIi1,
    const unsigned int* __restrict__ recsU, const int2* __restrict__ rowseU,
    uint2* __restrict__ u12) {
  int gw = (blockIdx.x * 256 + threadIdx.x) >> 6;
  int lane = threadIdx.x & 63;
  int sub = lane & 15, q = lane >> 4;
  if (gw >= U_CNT) return;
  int2 se = rowseU[gw];
  float4 a, b;
  gather_ebIi1_dual<16>(ebIi1, recsU, se.x, se.y, sub, q, a, b);
  if (q == 0)
    u12[(size_t)gw * 16 + sub] = make_uint2(pack_fp8x4(a), pack_fp8x4(b));
}

// k3: out = e_item + 0.5*i1 + (1/3)*spmm_iu(u1) + 0.25*spmm_iu(u2)
__global__ __launch_bounds__(256) void hop2b_kernel(
    const uint4* __restrict__ ebIi1, const uint2* __restrict__ u12,
    const unsigned int* __restrict__ recsI, const int2* __restrict__ rowseI,
    const float* __restrict__ e_item, float* __restrict__ out) {
  int gw = (blockIdx.x * 256 + threadIdx.x) >> 6;
  int lane = threadIdx.x & 63;
  int sub = lane & 15, q = lane >> 4;
  if (gw >= I_CNT) return;
  int2 se = rowseI[gw];
  float4 a, b;
  gather_fp8_dual2<32>(u12, recsI, se.x, se.y, sub, q, a, b);
  if (q == 0) {
    size_t idx = (size_t)gw * 16 + sub;
    float4 e = ((const float4*)e_item)[idx];
    uint4 t4 = ebIi1[idx];                      // .zw = i1 bf16x4
    const float c1 = 0.5f, c2 = (float)(1.0 / 3.0), c3 = 0.25f;
    float4 o;
    o.x = e.x + c1 * __uint_as_float(t4.z << 16)         + c2 * a.x + c3 * b.x;
    o.y = e.y + c1 * __uint_as_float(t4.z & 0xffff0000u) + c2 * a.y + c3 * b.y;
    o.z = e.z + c1 * __uint_as_float(t4.w << 16)         + c2 * a.z + c3 * b.z;
    o.w = e.w + c1 * __uint_as_float(t4.w & 0xffff0000u) + c2 * a.w + c3 * b.w;
    ((float4*)out)[idx] = o;
  }
}

extern "C" void kernel_launch(void* const* d_in, const int* in_sizes, int n_in,
                              void* d_out, int out_size, void* d_ws, size_t ws_size,
                              hipStream_t stream) {
  const float* embed_user = (const float*)d_in[0];  // [U, D]
  const float* embed_item = (const float*)d_in[1];  // [I, D]
  const float* edge_vals  = (const float*)d_in[2];  // [E]
  const int*   u_idx      = (const int*)d_in[3];    // [E]
  const int*   i_idx      = (const int*)d_in[4];    // [E]
  float* out = (float*)d_out;                       // [I, D]

  auto align256 = [](size_t x) { return (x + 255) & ~(size_t)255; };
  char* ws = (char*)d_ws;
  size_t off = 0;
  const size_t capRecs = (size_t)NB * CAP_B;                          // 2,097,152
  const size_t uHalf = (size_t)U_CNT * DIM * sizeof(unsigned short);  // 12.8 MB
  const size_t iIntl = (size_t)I_CNT * 16 * sizeof(uint4);            // 12.8 MB

  unsigned int* recsU = (unsigned int*)(ws + off); off += align256(capRecs * 4);
  unsigned int* recsI = (unsigned int*)(ws + off); off += align256(capRecs * 4);
  unsigned short* dlU = (unsigned short*)(ws + off); off += align256(capRecs * 2);
  unsigned short* dlI = (unsigned short*)(ws + off); off += align256(capRecs * 2);
  unsigned short* ebUb = (unsigned short*)(ws + off); off += align256(uHalf);
  uint4* ebIi1 = (uint4*)(ws + off); off += align256(iIntl);  // ebI | i1 interleaved
  uint2* u12   = (uint2*)(ws + off); off += align256(uHalf);  // u1 | u2 interleaved fp8
  int2* rowseU = (int2*)(ws + off); off += align256((size_t)U_CNT * sizeof(int2));
  int2* rowseI = (int2*)(ws + off); off += align256((size_t)I_CNT * sizeof(int2));
  int* cursU   = (int*)(ws + off);  off += align256(2 * NB * sizeof(int));
  int* cursI   = cursU + NB;        // contiguous -> single memset
  (void)ws_size;

  dim3 blk(256);

  // ---- build: partition + bf16 conversion in ONE launch ----
  hipMemsetAsync(cursU, 0, 2 * NB * sizeof(int), stream);
  const int p1blocks = (E_CNT + T1 - 1) / T1;  // 306
  build_kernel<<<p1blocks + CONVB, blk, 0, stream>>>(
      u_idx, i_idx, edge_vals, cursU, cursI, recsU, recsI, dlU, dlI,
      embed_user, ebUb, embed_item, (uint2*)ebIi1, E_CNT, p1blocks);

  const int nbValidU = (U_CNT + (1 << SHIFT_U) - 1) >> SHIFT_U;  // 196
  const int nbValidI = (I_CNT + (1 << SHIFT_I) - 1) >> SHIFT_I;  // 196
  csr_finalize_both<<<nbValidU + nbValidI, blk, 0, stream>>>(
      cursU, cursI, recsU, recsI, dlU, dlI, rowseU, rowseI, nbValidU);

  // ---- hops ----
  hop1i_kernel<<<(I_CNT + 3) / 4, blk, 0, stream>>>(ebUb, recsI, rowseI,
                                                    (uint2*)ebIi1);
  hop1u_kernel<<<(U_CNT + 3) / 4, blk, 0, stream>>>(ebIi1, recsU, rowseU, u12);
  hop2b_kernel<<<(I_CNT + 3) / 4, blk, 0, stream>>>(ebIi1, u12, recsI, rowseI,
                                                    embed_item, out);
}